// Round 1
// baseline (669.058 us; speedup 1.0000x reference)
//
#include <hip/hip_runtime.h>

// GCNEncoder: two GCNConv(+relu) layers + global mean pool.
// N=50000 nodes, E=1.6M edges, 128 ch in/out, 64 graphs.
// Strategy: build destination-CSR once per call (shared by both layers),
// fp32 GEMM with W in LDS, per-node wave aggregation (no wide atomics).

#define CH 128

__global__ void k_init(float* deg, int* cnt, int n) {
    int i = blockIdx.x * 256 + threadIdx.x;
    if (i < n) { deg[i] = 1.0f; cnt[i] = 0; }  // self-loop weight 1
}

__global__ void k_edge_deg(const int* __restrict__ col, const float* __restrict__ ew,
                           float* deg, int* cnt, int E) {
    int e = blockIdx.x * 256 + threadIdx.x;
    if (e < E) {
        int c = col[e];
        atomicAdd(&deg[c], ew[e]);
        atomicAdd(&cnt[c], 1);
    }
}

__global__ void k_rsqrt(float* deg, int n) {
    int i = blockIdx.x * 256 + threadIdx.x;
    if (i < n) deg[i] = rsqrtf(deg[i]);  // deg >= 1 always (self-loop)
}

// Single-block exclusive scan of cnt -> rowptr; also seeds cursor (=cnt array) with rowptr.
__global__ __launch_bounds__(1024) void k_scan(int* cnt_cursor, int* rowptr, int n) {
    __shared__ int sd[1024];
    int t = threadIdx.x;
    int chunk = (n + 1023) / 1024;
    int s = t * chunk, e = min(s + chunk, n);
    int sum = 0;
    for (int i = s; i < e; ++i) sum += cnt_cursor[i];
    sd[t] = sum;
    __syncthreads();
    for (int off = 1; off < 1024; off <<= 1) {
        int v = (t >= off) ? sd[t - off] : 0;
        __syncthreads();
        sd[t] += v;
        __syncthreads();
    }
    int run = sd[t] - sum;  // exclusive prefix
    for (int i = s; i < e; ++i) {
        int c = cnt_cursor[i];
        rowptr[i] = run;
        cnt_cursor[i] = run;  // becomes scatter cursor
        run += c;
    }
    if (t == 1023) rowptr[n] = sd[1023];
}

__global__ void k_scatter(const int* __restrict__ row, const int* __restrict__ col,
                          const float* __restrict__ ew, const float* __restrict__ dis,
                          int* cursor, int2* pairs, int E) {
    int e = blockIdx.x * 256 + threadIdx.x;
    if (e < E) {
        int r = row[e], c = col[e];
        float nrm = dis[r] * ew[e] * dis[c];
        int pos = atomicAdd(&cursor[c], 1);
        pairs[pos] = make_int2(r, __float_as_int(nrm));
    }
}

// Y[N,128] = X[N,128] @ W[128,128], fp32. W + 32-row X tile in LDS.
__global__ __launch_bounds__(256) void k_gemm(const float* __restrict__ X,
                                              const float* __restrict__ W,
                                              float* __restrict__ Y, int N) {
    __shared__ float Ws[128][128];  // 64 KiB
    __shared__ float Xs[32][128];   // 16 KiB
    int tid = threadIdx.x;
    {
        const float4* Wv = (const float4*)W;
        float4* Sv = (float4*)&Ws[0][0];
#pragma unroll
        for (int i = 0; i < 16; ++i) Sv[tid + 256 * i] = Wv[tid + 256 * i];
    }
    int row0 = blockIdx.x * 32;
    {
        float4* Xsv = (float4*)&Xs[0][0];
        if (row0 + 32 <= N) {
            const float4* Xv = (const float4*)(X + (size_t)row0 * CH);
#pragma unroll
            for (int i = 0; i < 4; ++i) { int idx = tid + 256 * i; Xsv[idx] = Xv[idx]; }
        } else {
#pragma unroll
            for (int i = 0; i < 4; ++i) {
                int idx = tid + 256 * i;
                int r = idx >> 5;
                float4 v = make_float4(0.f, 0.f, 0.f, 0.f);
                if (row0 + r < N) v = ((const float4*)(X + (size_t)(row0 + r) * CH))[idx & 31];
                Xsv[idx] = v;
            }
        }
    }
    __syncthreads();
    int c4 = tid & 31;   // col group: cols 4*c4 .. 4*c4+3
    int rl = tid >> 5;   // 0..7 -> rows rl, rl+8, rl+16, rl+24
    float4 acc[4];
#pragma unroll
    for (int j = 0; j < 4; ++j) acc[j] = make_float4(0.f, 0.f, 0.f, 0.f);
    for (int k = 0; k < 128; k += 4) {
        float4 w0 = *(const float4*)&Ws[k + 0][c4 * 4];
        float4 w1 = *(const float4*)&Ws[k + 1][c4 * 4];
        float4 w2 = *(const float4*)&Ws[k + 2][c4 * 4];
        float4 w3 = *(const float4*)&Ws[k + 3][c4 * 4];
#pragma unroll
        for (int j = 0; j < 4; ++j) {
            float4 xv = *(const float4*)&Xs[rl + 8 * j][k];
            acc[j].x += xv.x * w0.x + xv.y * w1.x + xv.z * w2.x + xv.w * w3.x;
            acc[j].y += xv.x * w0.y + xv.y * w1.y + xv.z * w2.y + xv.w * w3.y;
            acc[j].z += xv.x * w0.z + xv.y * w1.z + xv.z * w2.z + xv.w * w3.z;
            acc[j].w += xv.x * w0.w + xv.y * w1.w + xv.z * w2.w + xv.w * w3.w;
        }
    }
#pragma unroll
    for (int j = 0; j < 4; ++j) {
        int r = row0 + rl + 8 * j;
        if (r < N) *(float4*)&Y[(size_t)r * CH + c4 * 4] = acc[j];
    }
}

// One wave per node: out[n] = relu( selfnorm*xw[n] + sum_e nrm_e * xw[src_e] + bias )
__global__ __launch_bounds__(64) void k_agg(const float* __restrict__ XW,
                                            const float* __restrict__ dis,
                                            const int* __restrict__ rowptr,
                                            const int2* __restrict__ pairs,
                                            const float* __restrict__ bias,
                                            float* __restrict__ OUT, int N) {
    int n = blockIdx.x;
    if (n >= N) return;
    int lane = threadIdx.x;  // 64 lanes, 2 ch each
    const float2* xw2 = (const float2*)XW;
    float d = dis[n];
    float sn = d * d;  // self-loop norm = 1/deg
    float2 a = xw2[(size_t)n * 64 + lane];
    float ax = a.x * sn, ay = a.y * sn;
    int e0 = rowptr[n], e1 = rowptr[n + 1];
    int e = e0;
    for (; e + 4 <= e1; e += 4) {
        int2 p0 = pairs[e], p1 = pairs[e + 1], p2 = pairs[e + 2], p3 = pairs[e + 3];
        float2 v0 = xw2[(size_t)p0.x * 64 + lane];
        float2 v1 = xw2[(size_t)p1.x * 64 + lane];
        float2 v2 = xw2[(size_t)p2.x * 64 + lane];
        float2 v3 = xw2[(size_t)p3.x * 64 + lane];
        float n0 = __int_as_float(p0.y), n1 = __int_as_float(p1.y);
        float n2 = __int_as_float(p2.y), n3 = __int_as_float(p3.y);
        ax += n0 * v0.x + n1 * v1.x + n2 * v2.x + n3 * v3.x;
        ay += n0 * v0.y + n1 * v1.y + n2 * v2.y + n3 * v3.y;
    }
    for (; e < e1; ++e) {
        int2 p = pairs[e];
        float2 v = xw2[(size_t)p.x * 64 + lane];
        float nn = __int_as_float(p.y);
        ax += nn * v.x;
        ay += nn * v.y;
    }
    float2 b = ((const float2*)bias)[lane];
    ax = fmaxf(ax + b.x, 0.f);
    ay = fmaxf(ay + b.y, 0.f);
    ((float2*)OUT)[(size_t)n * 64 + lane] = make_float2(ax, ay);
}

__device__ __forceinline__ int lowerb(const int* a, int n, int v) {
    int lo = 0, hi = n;
    while (lo < hi) {
        int m = (lo + hi) >> 1;
        if (a[m] < v) lo = m + 1; else hi = m;
    }
    return lo;
}

// batch is sorted: one block per graph, 128 threads (one per channel).
__global__ __launch_bounds__(128) void k_pool(const float* __restrict__ H,
                                              const int* __restrict__ batch,
                                              float* __restrict__ P, int N) {
    __shared__ int ss[2];
    int g = blockIdx.x;
    if (threadIdx.x == 0) {
        ss[0] = lowerb(batch, N, g);
        ss[1] = lowerb(batch, N, g + 1);
    }
    __syncthreads();
    int s = ss[0], e = ss[1];
    int ch = threadIdx.x;
    float a0 = 0.f, a1 = 0.f, a2 = 0.f, a3 = 0.f;
    int n = s;
    for (; n + 4 <= e; n += 4) {
        a0 += H[(size_t)(n + 0) * CH + ch];
        a1 += H[(size_t)(n + 1) * CH + ch];
        a2 += H[(size_t)(n + 2) * CH + ch];
        a3 += H[(size_t)(n + 3) * CH + ch];
    }
    for (; n < e; ++n) a0 += H[(size_t)n * CH + ch];
    float sum = (a0 + a1) + (a2 + a3);
    float c = (float)(e - s);
    P[(size_t)g * CH + ch] = sum / fmaxf(c, 1.f);
}

extern "C" void kernel_launch(void* const* d_in, const int* in_sizes, int n_in,
                              void* d_out, int out_size, void* d_ws, size_t ws_size,
                              hipStream_t stream) {
    const float* x     = (const float*)d_in[0];
    const int*   ei    = (const int*)d_in[1];
    const float* ew    = (const float*)d_in[2];
    const int*   batch = (const int*)d_in[3];
    const float* W1    = (const float*)d_in[4];
    const float* b1    = (const float*)d_in[5];
    const float* W2    = (const float*)d_in[6];
    const float* b2    = (const float*)d_in[7];

    int N = in_sizes[0] / CH;       // 50000
    int E = in_sizes[1] / 2;        // 1600000
    const int* row = ei;
    const int* col = ei + E;

    float* out    = (float*)d_out;
    float* h      = out;                      // [N,128] final h, also temp h1
    float* pooled = out + (size_t)N * CH;     // [64,128]

    // ws layout (256B-aligned slabs)
    char* wsb = (char*)d_ws;
    size_t oN  = ((size_t)N * 4 + 255) & ~(size_t)255;
    size_t oN1 = ((size_t)(N + 1) * 4 + 255) & ~(size_t)255;
    size_t oE  = ((size_t)E * 8 + 255) & ~(size_t)255;
    float* dis    = (float*)wsb;                          // deg, then rsqrt(deg)
    int*   rowptr = (int*)(wsb + oN);
    int*   cursor = (int*)(wsb + oN + oN1);
    int2*  pairs  = (int2*)(wsb + oN + oN1 + oN);
    float* xw     = (float*)(wsb + oN + oN1 + oN + oE);   // [N,128]

    int nb = (N + 255) / 256;
    int eb = (E + 255) / 256;

    // ---- CSR build (shared by both layers) ----
    k_init<<<nb, 256, 0, stream>>>(dis, cursor, N);
    k_edge_deg<<<eb, 256, 0, stream>>>(col, ew, dis, cursor, E);
    k_rsqrt<<<nb, 256, 0, stream>>>(dis, N);
    k_scan<<<1, 1024, 0, stream>>>(cursor, rowptr, N);
    k_scatter<<<eb, 256, 0, stream>>>(row, col, ew, dis, cursor, pairs, E);

    int gb = (N + 31) / 32;
    // ---- layer 1 ----
    k_gemm<<<gb, 256, 0, stream>>>(x, W1, xw, N);
    k_agg<<<N, 64, 0, stream>>>(xw, dis, rowptr, pairs, b1, h, N);
    // ---- layer 2 (h1 lives in d_out, overwritten by layer-2 result) ----
    k_gemm<<<gb, 256, 0, stream>>>(h, W2, xw, N);
    k_agg<<<N, 64, 0, stream>>>(xw, dis, rowptr, pairs, b2, h, N);
    // ---- mean pool ----
    k_pool<<<64, 128, 0, stream>>>(h, batch, pooled, N);
}

// Round 2
// 470.963 us; speedup vs baseline: 1.4206x; 1.4206x over previous
//
#include <hip/hip_runtime.h>

// GCNEncoder: two GCNConv(+relu) layers + global mean pool.
// N=50000 nodes, E=1.6M edges, 128 ch, 64 graphs.
// R1: single atomic pass (count returns ordinal), atomic-free scatter,
// deg/norm from CSR segments, grid-wide 3-phase scan.

#define CH 128

__global__ void k_zero(int* cnt, int n) {
    int i = blockIdx.x * 256 + threadIdx.x;
    if (i < n) cnt[i] = 0;
}

// ord[e] = position of edge e within its destination's segment (free from atomic return)
__global__ void k_count(const int* __restrict__ col, int* cnt, int* __restrict__ ord, int E) {
    int e = blockIdx.x * 256 + threadIdx.x;
    if (e < E) ord[e] = atomicAdd(&cnt[col[e]], 1);
}

// ---- 3-phase exclusive scan of cnt[0..n) -> rowptr[0..n] ----
__global__ __launch_bounds__(1024) void k_scan1(const int* __restrict__ cnt, int* __restrict__ rp,
                                                int* __restrict__ bsum, int n) {
    __shared__ int sd[1024];
    int t = threadIdx.x;
    int i = blockIdx.x * 1024 + t;
    int v = (i < n) ? cnt[i] : 0;
    sd[t] = v;
    __syncthreads();
    for (int off = 1; off < 1024; off <<= 1) {
        int u = (t >= off) ? sd[t - off] : 0;
        __syncthreads();
        sd[t] += u;
        __syncthreads();
    }
    if (i < n) rp[i] = sd[t] - v;  // block-local exclusive
    if (t == 1023) bsum[blockIdx.x] = sd[1023];
}

__global__ __launch_bounds__(64) void k_scan2(int* bsum, int nb, int* rp_end) {
    int t = threadIdx.x;
    if (nb <= 64) {
        int v = (t < nb) ? bsum[t] : 0;
        int orig = v;
        for (int off = 1; off < 64; off <<= 1) {
            int u = __shfl_up(v, off);
            if (t >= off) v += u;
        }
        if (t < nb) bsum[t] = v - orig;     // exclusive block offsets
        if (t == nb - 1) *rp_end = v;       // grand total
    } else if (t == 0) {
        int run = 0;
        for (int i = 0; i < nb; ++i) { int c = bsum[i]; bsum[i] = run; run += c; }
        *rp_end = run;
    }
}

__global__ void k_scan3(int* rp, const int* __restrict__ bsum, int n) {
    int i = blockIdx.x * 256 + threadIdx.x;
    if (i < n) rp[i] += bsum[i >> 10];
}

// Atomic-free scatter: slot = rowptr[col] + ord. Pair = {src, weight}.
__global__ void k_scatter(const int* __restrict__ row, const int* __restrict__ col,
                          const float* __restrict__ ew, const int* __restrict__ ord,
                          const int* __restrict__ rowptr, int2* __restrict__ pairs, int E) {
    int e = blockIdx.x * 256 + threadIdx.x;
    if (e < E) {
        int c = col[e];
        int pos = rowptr[c] + ord[e];
        pairs[pos] = make_int2(row[e], __float_as_int(ew[e]));
    }
}

// dis[n] = rsqrt(1 + sum of incoming edge weights) — wave per node, coalesced.
__global__ __launch_bounds__(64) void k_deg(const int* __restrict__ rowptr,
                                            const int2* __restrict__ pairs,
                                            float* __restrict__ dis, int N) {
    int n = blockIdx.x;
    int lane = threadIdx.x;
    int e0 = rowptr[n], e1 = rowptr[n + 1];
    float s = 0.f;
    for (int e = e0 + lane; e < e1; e += 64) s += __int_as_float(pairs[e].y);
    for (int off = 32; off; off >>= 1) s += __shfl_xor(s, off);
    if (lane == 0) dis[n] = rsqrtf(1.0f + s);
}

// pairs[e].y: weight -> norm = dis[n] * w * dis[src]
__global__ __launch_bounds__(64) void k_norm(const int* __restrict__ rowptr,
                                             int2* __restrict__ pairs,
                                             const float* __restrict__ dis, int N) {
    int n = blockIdx.x;
    int lane = threadIdx.x;
    float dn = dis[n];
    int e0 = rowptr[n], e1 = rowptr[n + 1];
    for (int e = e0 + lane; e < e1; e += 64) {
        int2 p = pairs[e];
        float nn = dn * __int_as_float(p.y) * dis[p.x];
        pairs[e].y = __float_as_int(nn);
    }
}

// Y[N,128] = X[N,128] @ W[128,128], fp32. W + 32-row X tile in LDS.
__global__ __launch_bounds__(256) void k_gemm(const float* __restrict__ X,
                                              const float* __restrict__ W,
                                              float* __restrict__ Y, int N) {
    __shared__ float Ws[128][128];  // 64 KiB
    __shared__ float Xs[32][128];   // 16 KiB
    int tid = threadIdx.x;
    {
        const float4* Wv = (const float4*)W;
        float4* Sv = (float4*)&Ws[0][0];
#pragma unroll
        for (int i = 0; i < 16; ++i) Sv[tid + 256 * i] = Wv[tid + 256 * i];
    }
    int row0 = blockIdx.x * 32;
    {
        float4* Xsv = (float4*)&Xs[0][0];
        if (row0 + 32 <= N) {
            const float4* Xv = (const float4*)(X + (size_t)row0 * CH);
#pragma unroll
            for (int i = 0; i < 4; ++i) { int idx = tid + 256 * i; Xsv[idx] = Xv[idx]; }
        } else {
#pragma unroll
            for (int i = 0; i < 4; ++i) {
                int idx = tid + 256 * i;
                int r = idx >> 5;
                float4 v = make_float4(0.f, 0.f, 0.f, 0.f);
                if (row0 + r < N) v = ((const float4*)(X + (size_t)(row0 + r) * CH))[idx & 31];
                Xsv[idx] = v;
            }
        }
    }
    __syncthreads();
    int c4 = tid & 31;
    int rl = tid >> 5;
    float4 acc[4];
#pragma unroll
    for (int j = 0; j < 4; ++j) acc[j] = make_float4(0.f, 0.f, 0.f, 0.f);
    for (int k = 0; k < 128; k += 4) {
        float4 w0 = *(const float4*)&Ws[k + 0][c4 * 4];
        float4 w1 = *(const float4*)&Ws[k + 1][c4 * 4];
        float4 w2 = *(const float4*)&Ws[k + 2][c4 * 4];
        float4 w3 = *(const float4*)&Ws[k + 3][c4 * 4];
#pragma unroll
        for (int j = 0; j < 4; ++j) {
            float4 xv = *(const float4*)&Xs[rl + 8 * j][k];
            acc[j].x += xv.x * w0.x + xv.y * w1.x + xv.z * w2.x + xv.w * w3.x;
            acc[j].y += xv.x * w0.y + xv.y * w1.y + xv.z * w2.y + xv.w * w3.y;
            acc[j].z += xv.x * w0.z + xv.y * w1.z + xv.z * w2.z + xv.w * w3.z;
            acc[j].w += xv.x * w0.w + xv.y * w1.w + xv.z * w2.w + xv.w * w3.w;
        }
    }
#pragma unroll
    for (int j = 0; j < 4; ++j) {
        int r = row0 + rl + 8 * j;
        if (r < N) *(float4*)&Y[(size_t)r * CH + c4 * 4] = acc[j];
    }
}

// One wave per node: out[n] = relu( selfnorm*xw[n] + sum_e nrm_e * xw[src_e] + bias )
__global__ __launch_bounds__(64) void k_agg(const float* __restrict__ XW,
                                            const float* __restrict__ dis,
                                            const int* __restrict__ rowptr,
                                            const int2* __restrict__ pairs,
                                            const float* __restrict__ bias,
                                            float* __restrict__ OUT, int N) {
    int n = blockIdx.x;
    if (n >= N) return;
    int lane = threadIdx.x;
    const float2* xw2 = (const float2*)XW;
    float d = dis[n];
    float sn = d * d;
    float2 a = xw2[(size_t)n * 64 + lane];
    float ax = a.x * sn, ay = a.y * sn;
    int e0 = rowptr[n], e1 = rowptr[n + 1];
    int e = e0;
    for (; e + 4 <= e1; e += 4) {
        int2 p0 = pairs[e], p1 = pairs[e + 1], p2 = pairs[e + 2], p3 = pairs[e + 3];
        float2 v0 = xw2[(size_t)p0.x * 64 + lane];
        float2 v1 = xw2[(size_t)p1.x * 64 + lane];
        float2 v2 = xw2[(size_t)p2.x * 64 + lane];
        float2 v3 = xw2[(size_t)p3.x * 64 + lane];
        float n0 = __int_as_float(p0.y), n1 = __int_as_float(p1.y);
        float n2 = __int_as_float(p2.y), n3 = __int_as_float(p3.y);
        ax += n0 * v0.x + n1 * v1.x + n2 * v2.x + n3 * v3.x;
        ay += n0 * v0.y + n1 * v1.y + n2 * v2.y + n3 * v3.y;
    }
    for (; e < e1; ++e) {
        int2 p = pairs[e];
        float2 v = xw2[(size_t)p.x * 64 + lane];
        float nn = __int_as_float(p.y);
        ax += nn * v.x;
        ay += nn * v.y;
    }
    float2 b = ((const float2*)bias)[lane];
    ax = fmaxf(ax + b.x, 0.f);
    ay = fmaxf(ay + b.y, 0.f);
    ((float2*)OUT)[(size_t)n * 64 + lane] = make_float2(ax, ay);
}

__device__ __forceinline__ int lowerb(const int* a, int n, int v) {
    int lo = 0, hi = n;
    while (lo < hi) {
        int m = (lo + hi) >> 1;
        if (a[m] < v) lo = m + 1; else hi = m;
    }
    return lo;
}

__global__ __launch_bounds__(128) void k_pool(const float* __restrict__ H,
                                              const int* __restrict__ batch,
                                              float* __restrict__ P, int N) {
    __shared__ int ss[2];
    int g = blockIdx.x;
    if (threadIdx.x == 0) {
        ss[0] = lowerb(batch, N, g);
        ss[1] = lowerb(batch, N, g + 1);
    }
    __syncthreads();
    int s = ss[0], e = ss[1];
    int ch = threadIdx.x;
    float a0 = 0.f, a1 = 0.f, a2 = 0.f, a3 = 0.f;
    int n = s;
    for (; n + 4 <= e; n += 4) {
        a0 += H[(size_t)(n + 0) * CH + ch];
        a1 += H[(size_t)(n + 1) * CH + ch];
        a2 += H[(size_t)(n + 2) * CH + ch];
        a3 += H[(size_t)(n + 3) * CH + ch];
    }
    for (; n < e; ++n) a0 += H[(size_t)n * CH + ch];
    float sum = (a0 + a1) + (a2 + a3);
    float c = (float)(e - s);
    P[(size_t)g * CH + ch] = sum / fmaxf(c, 1.f);
}

extern "C" void kernel_launch(void* const* d_in, const int* in_sizes, int n_in,
                              void* d_out, int out_size, void* d_ws, size_t ws_size,
                              hipStream_t stream) {
    const float* x     = (const float*)d_in[0];
    const int*   ei    = (const int*)d_in[1];
    const float* ew    = (const float*)d_in[2];
    const int*   batch = (const int*)d_in[3];
    const float* W1    = (const float*)d_in[4];
    const float* b1    = (const float*)d_in[5];
    const float* W2    = (const float*)d_in[6];
    const float* b2    = (const float*)d_in[7];

    int N = in_sizes[0] / CH;   // 50000
    int E = in_sizes[1] / 2;    // 1600000
    const int* row = ei;
    const int* col = ei + E;

    float* out    = (float*)d_out;
    float* h      = out;
    float* pooled = out + (size_t)N * CH;

    // ws layout: dis | rowptr | cnt | bsum | pairs | xw (ord aliases xw)
    char* wsb = (char*)d_ws;
    size_t oN  = ((size_t)N * 4 + 255) & ~(size_t)255;
    size_t oN1 = ((size_t)(N + 1) * 4 + 255) & ~(size_t)255;
    size_t oB  = 256;  // up to 64 block sums
    size_t oE2 = ((size_t)E * 8 + 255) & ~(size_t)255;
    float* dis    = (float*)wsb;
    int*   rowptr = (int*)(wsb + oN);
    int*   cnt    = (int*)(wsb + oN + oN1);
    int*   bsum   = (int*)(wsb + oN + oN1 + oN);
    int2*  pairs  = (int2*)(wsb + oN + oN1 + oN + oB);
    float* xw     = (float*)(wsb + oN + oN1 + oN + oB + oE2);
    int*   ord    = (int*)xw;  // E ints <= N*128 floats; dead before gemm writes xw

    int nb = (N + 255) / 256;
    int eb = (E + 255) / 256;
    int sb = (N + 1023) / 1024;  // scan blocks (49)

    // ---- CSR build (one atomic pass) ----
    k_zero<<<nb, 256, 0, stream>>>(cnt, N);
    k_count<<<eb, 256, 0, stream>>>(col, cnt, ord, E);
    k_scan1<<<sb, 1024, 0, stream>>>(cnt, rowptr, bsum, N);
    k_scan2<<<1, 64, 0, stream>>>(bsum, sb, rowptr + N);
    k_scan3<<<nb, 256, 0, stream>>>(rowptr, bsum, N);
    k_scatter<<<eb, 256, 0, stream>>>(row, col, ew, ord, rowptr, pairs, E);
    k_deg<<<N, 64, 0, stream>>>(rowptr, pairs, dis, N);
    k_norm<<<N, 64, 0, stream>>>(rowptr, pairs, dis, N);

    int gb = (N + 31) / 32;
    // ---- layer 1 ----
    k_gemm<<<gb, 256, 0, stream>>>(x, W1, xw, N);
    k_agg<<<N, 64, 0, stream>>>(xw, dis, rowptr, pairs, b1, h, N);
    // ---- layer 2 ----
    k_gemm<<<gb, 256, 0, stream>>>(h, W2, xw, N);
    k_agg<<<N, 64, 0, stream>>>(xw, dis, rowptr, pairs, b2, h, N);
    // ---- mean pool ----
    k_pool<<<64, 128, 0, stream>>>(h, batch, pooled, N);
}

// Round 3
// 361.700 us; speedup vs baseline: 1.8498x; 1.3021x over previous
//
#include <hip/hip_runtime.h>

// GCNEncoder: two GCNConv(+relu) layers + global mean pool.
// N=50000 nodes, E=1.6M edges, 128 ch, 64 graphs.
// R2: bf16 xw (halves the random-gather bytes in k_agg), 8-way privatized
// count histogram (cuts same-address atomic chains 32->4).

#define CH 128
#define NPRIV 8

static __device__ __forceinline__ unsigned short f2bf(float f) {
    unsigned u = __float_as_uint(f);
    unsigned r = (u + 0x7FFF + ((u >> 16) & 1)) >> 16;  // RNE
    return (unsigned short)r;
}

__global__ void k_zero(int* cnt, int n) {
    int i = blockIdx.x * 256 + threadIdx.x;
    if (i < n) cnt[i] = 0;
}

// ord[e] = rank within (private-histogram p, destination c)
__global__ void k_count(const int* __restrict__ col, int* cnt, int* __restrict__ ord,
                        int E, int N) {
    int e = blockIdx.x * 256 + threadIdx.x;
    if (e < E) {
        int p = blockIdx.x & (NPRIV - 1);
        ord[e] = atomicAdd(&cnt[p * N + col[e]], 1);
    }
}

// Per node: total over 8 private counts -> scan; also write per-p exclusive
// offsets back into cnt (becomes poff for the scatter).
__global__ __launch_bounds__(1024) void k_scan1(int* __restrict__ cnt, int* __restrict__ rp,
                                                int* __restrict__ bsum, int n) {
    __shared__ int sd[1024];
    int t = threadIdx.x;
    int i = blockIdx.x * 1024 + t;
    int v = 0;
    if (i < n) {
        int run = 0;
#pragma unroll
        for (int p = 0; p < NPRIV; ++p) {
            int c = cnt[p * n + i];
            cnt[p * n + i] = run;  // exclusive prefix across private copies
            run += c;
        }
        v = run;
    }
    sd[t] = v;
    __syncthreads();
    for (int off = 1; off < 1024; off <<= 1) {
        int u = (t >= off) ? sd[t - off] : 0;
        __syncthreads();
        sd[t] += u;
        __syncthreads();
    }
    if (i < n) rp[i] = sd[t] - v;  // block-local exclusive
    if (t == 1023) bsum[blockIdx.x] = sd[1023];
}

__global__ __launch_bounds__(64) void k_scan2(int* bsum, int nb, int* rp_end) {
    int t = threadIdx.x;
    if (nb <= 64) {
        int v = (t < nb) ? bsum[t] : 0;
        int orig = v;
        for (int off = 1; off < 64; off <<= 1) {
            int u = __shfl_up(v, off);
            if (t >= off) v += u;
        }
        if (t < nb) bsum[t] = v - orig;
        if (t == nb - 1) *rp_end = v;
    } else if (t == 0) {
        int run = 0;
        for (int i = 0; i < nb; ++i) { int c = bsum[i]; bsum[i] = run; run += c; }
        *rp_end = run;
    }
}

__global__ void k_scan3(int* rp, const int* __restrict__ bsum, int n) {
    int i = blockIdx.x * 256 + threadIdx.x;
    if (i < n) rp[i] += bsum[i >> 10];
}

// Atomic-free scatter: slot = rowptr[c] + poff[p][c] + ord[e]. Pair = {src, w}.
__global__ void k_scatter(const int* __restrict__ row, const int* __restrict__ col,
                          const float* __restrict__ ew, const int* __restrict__ ord,
                          const int* __restrict__ rowptr, const int* __restrict__ poff,
                          int2* __restrict__ pairs, int E, int N) {
    int e = blockIdx.x * 256 + threadIdx.x;
    if (e < E) {
        int p = blockIdx.x & (NPRIV - 1);  // must match k_count
        int c = col[e];
        int pos = rowptr[c] + poff[p * N + c] + ord[e];
        pairs[pos] = make_int2(row[e], __float_as_int(ew[e]));
    }
}

// dis[n] = rsqrt(1 + sum of incoming edge weights)
__global__ __launch_bounds__(64) void k_deg(const int* __restrict__ rowptr,
                                            const int2* __restrict__ pairs,
                                            float* __restrict__ dis, int N) {
    int n = blockIdx.x;
    int lane = threadIdx.x;
    int e0 = rowptr[n], e1 = rowptr[n + 1];
    float s = 0.f;
    for (int e = e0 + lane; e < e1; e += 64) s += __int_as_float(pairs[e].y);
    for (int off = 32; off; off >>= 1) s += __shfl_xor(s, off);
    if (lane == 0) dis[n] = rsqrtf(1.0f + s);
}

// pairs[e].y: weight -> norm = dis[n] * w * dis[src]
__global__ __launch_bounds__(64) void k_norm(const int* __restrict__ rowptr,
                                             int2* __restrict__ pairs,
                                             const float* __restrict__ dis, int N) {
    int n = blockIdx.x;
    int lane = threadIdx.x;
    float dn = dis[n];
    int e0 = rowptr[n], e1 = rowptr[n + 1];
    for (int e = e0 + lane; e < e1; e += 64) {
        int2 p = pairs[e];
        float nn = dn * __int_as_float(p.y) * dis[p.x];
        pairs[e].y = __float_as_int(nn);
    }
}

// Y[N,128](bf16) = X[N,128](f32) @ W[128,128](f32). W + 32-row X tile in LDS.
__global__ __launch_bounds__(256) void k_gemm(const float* __restrict__ X,
                                              const float* __restrict__ W,
                                              unsigned short* __restrict__ Y, int N) {
    __shared__ float Ws[128][128];
    __shared__ float Xs[32][128];
    int tid = threadIdx.x;
    {
        const float4* Wv = (const float4*)W;
        float4* Sv = (float4*)&Ws[0][0];
#pragma unroll
        for (int i = 0; i < 16; ++i) Sv[tid + 256 * i] = Wv[tid + 256 * i];
    }
    int row0 = blockIdx.x * 32;
    {
        float4* Xsv = (float4*)&Xs[0][0];
        if (row0 + 32 <= N) {
            const float4* Xv = (const float4*)(X + (size_t)row0 * CH);
#pragma unroll
            for (int i = 0; i < 4; ++i) { int idx = tid + 256 * i; Xsv[idx] = Xv[idx]; }
        } else {
#pragma unroll
            for (int i = 0; i < 4; ++i) {
                int idx = tid + 256 * i;
                int r = idx >> 5;
                float4 v = make_float4(0.f, 0.f, 0.f, 0.f);
                if (row0 + r < N) v = ((const float4*)(X + (size_t)(row0 + r) * CH))[idx & 31];
                Xsv[idx] = v;
            }
        }
    }
    __syncthreads();
    int c4 = tid & 31;
    int rl = tid >> 5;
    float4 acc[4];
#pragma unroll
    for (int j = 0; j < 4; ++j) acc[j] = make_float4(0.f, 0.f, 0.f, 0.f);
    for (int k = 0; k < 128; k += 4) {
        float4 w0 = *(const float4*)&Ws[k + 0][c4 * 4];
        float4 w1 = *(const float4*)&Ws[k + 1][c4 * 4];
        float4 w2 = *(const float4*)&Ws[k + 2][c4 * 4];
        float4 w3 = *(const float4*)&Ws[k + 3][c4 * 4];
#pragma unroll
        for (int j = 0; j < 4; ++j) {
            float4 xv = *(const float4*)&Xs[rl + 8 * j][k];
            acc[j].x += xv.x * w0.x + xv.y * w1.x + xv.z * w2.x + xv.w * w3.x;
            acc[j].y += xv.x * w0.y + xv.y * w1.y + xv.z * w2.y + xv.w * w3.y;
            acc[j].z += xv.x * w0.z + xv.y * w1.z + xv.z * w2.z + xv.w * w3.z;
            acc[j].w += xv.x * w0.w + xv.y * w1.w + xv.z * w2.w + xv.w * w3.w;
        }
    }
#pragma unroll
    for (int j = 0; j < 4; ++j) {
        int r = row0 + rl + 8 * j;
        if (r < N) {
            ushort4 o;
            o.x = f2bf(acc[j].x); o.y = f2bf(acc[j].y);
            o.z = f2bf(acc[j].z); o.w = f2bf(acc[j].w);
            *(ushort4*)&Y[(size_t)r * CH + c4 * 4] = o;
        }
    }
}

// One wave per node: out[n] = relu( selfnorm*xw[n] + sum_e nrm_e*xw[src_e] + b ).
// xw is bf16 (2 ch per lane = 4B/lane, 256B/edge gather); accumulate fp32.
__global__ __launch_bounds__(64) void k_agg(const unsigned int* __restrict__ XW,
                                            const float* __restrict__ dis,
                                            const int* __restrict__ rowptr,
                                            const int2* __restrict__ pairs,
                                            const float* __restrict__ bias,
                                            float* __restrict__ OUT, int N) {
    int n = blockIdx.x;
    if (n >= N) return;
    int lane = threadIdx.x;
    float d = dis[n];
    float sn = d * d;
    unsigned a = XW[(size_t)n * 64 + lane];
    float ax = __uint_as_float(a << 16) * sn;
    float ay = __uint_as_float(a & 0xFFFF0000u) * sn;
    int e0 = rowptr[n], e1 = rowptr[n + 1];
    int e = e0;
    for (; e + 4 <= e1; e += 4) {
        int2 p0 = pairs[e], p1 = pairs[e + 1], p2 = pairs[e + 2], p3 = pairs[e + 3];
        unsigned v0 = XW[(size_t)p0.x * 64 + lane];
        unsigned v1 = XW[(size_t)p1.x * 64 + lane];
        unsigned v2 = XW[(size_t)p2.x * 64 + lane];
        unsigned v3 = XW[(size_t)p3.x * 64 + lane];
        float n0 = __int_as_float(p0.y), n1 = __int_as_float(p1.y);
        float n2 = __int_as_float(p2.y), n3 = __int_as_float(p3.y);
        ax += n0 * __uint_as_float(v0 << 16) + n1 * __uint_as_float(v1 << 16)
            + n2 * __uint_as_float(v2 << 16) + n3 * __uint_as_float(v3 << 16);
        ay += n0 * __uint_as_float(v0 & 0xFFFF0000u) + n1 * __uint_as_float(v1 & 0xFFFF0000u)
            + n2 * __uint_as_float(v2 & 0xFFFF0000u) + n3 * __uint_as_float(v3 & 0xFFFF0000u);
    }
    for (; e < e1; ++e) {
        int2 p = pairs[e];
        unsigned v = XW[(size_t)p.x * 64 + lane];
        float nn = __int_as_float(p.y);
        ax += nn * __uint_as_float(v << 16);
        ay += nn * __uint_as_float(v & 0xFFFF0000u);
    }
    float2 b = ((const float2*)bias)[lane];
    ax = fmaxf(ax + b.x, 0.f);
    ay = fmaxf(ay + b.y, 0.f);
    ((float2*)OUT)[(size_t)n * 64 + lane] = make_float2(ax, ay);
}

__device__ __forceinline__ int lowerb(const int* a, int n, int v) {
    int lo = 0, hi = n;
    while (lo < hi) {
        int m = (lo + hi) >> 1;
        if (a[m] < v) lo = m + 1; else hi = m;
    }
    return lo;
}

__global__ __launch_bounds__(128) void k_pool(const float* __restrict__ H,
                                              const int* __restrict__ batch,
                                              float* __restrict__ P, int N) {
    __shared__ int ss[2];
    int g = blockIdx.x;
    if (threadIdx.x == 0) {
        ss[0] = lowerb(batch, N, g);
        ss[1] = lowerb(batch, N, g + 1);
    }
    __syncthreads();
    int s = ss[0], e = ss[1];
    int ch = threadIdx.x;
    float a0 = 0.f, a1 = 0.f, a2 = 0.f, a3 = 0.f;
    int n = s;
    for (; n + 4 <= e; n += 4) {
        a0 += H[(size_t)(n + 0) * CH + ch];
        a1 += H[(size_t)(n + 1) * CH + ch];
        a2 += H[(size_t)(n + 2) * CH + ch];
        a3 += H[(size_t)(n + 3) * CH + ch];
    }
    for (; n < e; ++n) a0 += H[(size_t)n * CH + ch];
    float sum = (a0 + a1) + (a2 + a3);
    float c = (float)(e - s);
    P[(size_t)g * CH + ch] = sum / fmaxf(c, 1.f);
}

extern "C" void kernel_launch(void* const* d_in, const int* in_sizes, int n_in,
                              void* d_out, int out_size, void* d_ws, size_t ws_size,
                              hipStream_t stream) {
    const float* x     = (const float*)d_in[0];
    const int*   ei    = (const int*)d_in[1];
    const float* ew    = (const float*)d_in[2];
    const int*   batch = (const int*)d_in[3];
    const float* W1    = (const float*)d_in[4];
    const float* b1    = (const float*)d_in[5];
    const float* W2    = (const float*)d_in[6];
    const float* b2    = (const float*)d_in[7];

    int N = in_sizes[0] / CH;   // 50000
    int E = in_sizes[1] / 2;    // 1600000
    const int* row = ei;
    const int* col = ei + E;

    float* out    = (float*)d_out;
    float* h      = out;
    float* pooled = out + (size_t)N * CH;

    // ws: dis | rowptr | cnt(8N) | bsum | pairs | xw(bf16; ord aliases)
    char* wsb = (char*)d_ws;
    size_t oN  = ((size_t)N * 4 + 255) & ~(size_t)255;
    size_t oN1 = ((size_t)(N + 1) * 4 + 255) & ~(size_t)255;
    size_t oC  = ((size_t)NPRIV * N * 4 + 255) & ~(size_t)255;
    size_t oB  = 256;
    size_t oE2 = ((size_t)E * 8 + 255) & ~(size_t)255;
    float* dis    = (float*)wsb;
    int*   rowptr = (int*)(wsb + oN);
    int*   cnt    = (int*)(wsb + oN + oN1);               // 8 private histograms / poff
    int*   bsum   = (int*)(wsb + oN + oN1 + oC);
    int2*  pairs  = (int2*)(wsb + oN + oN1 + oC + oB);
    unsigned short* xw = (unsigned short*)(wsb + oN + oN1 + oC + oB + oE2);  // [N,128] bf16
    int*   ord    = (int*)xw;  // E ints (6.4MB) <= N*128*2B (12.8MB); dead before gemm

    int nb  = (N + 255) / 256;
    int nb8 = (NPRIV * N + 255) / 256;
    int eb  = (E + 255) / 256;
    int sb  = (N + 1023) / 1024;

    // ---- CSR build ----
    k_zero<<<nb8, 256, 0, stream>>>(cnt, NPRIV * N);
    k_count<<<eb, 256, 0, stream>>>(col, cnt, ord, E, N);
    k_scan1<<<sb, 1024, 0, stream>>>(cnt, rowptr, bsum, N);
    k_scan2<<<1, 64, 0, stream>>>(bsum, sb, rowptr + N);
    k_scan3<<<nb, 256, 0, stream>>>(rowptr, bsum, N);
    k_scatter<<<eb, 256, 0, stream>>>(row, col, ew, ord, rowptr, cnt, pairs, E, N);
    k_deg<<<N, 64, 0, stream>>>(rowptr, pairs, dis, N);
    k_norm<<<N, 64, 0, stream>>>(rowptr, pairs, dis, N);

    int gb = (N + 31) / 32;
    // ---- layer 1 ----
    k_gemm<<<gb, 256, 0, stream>>>(x, W1, xw, N);
    k_agg<<<N, 64, 0, stream>>>((const unsigned int*)xw, dis, rowptr, pairs, b1, h, N);
    // ---- layer 2 ----
    k_gemm<<<gb, 256, 0, stream>>>(h, W2, xw, N);
    k_agg<<<N, 64, 0, stream>>>((const unsigned int*)xw, dis, rowptr, pairs, b2, h, N);
    // ---- mean pool ----
    k_pool<<<64, 128, 0, stream>>>(h, batch, pooled, N);
}

// Round 4
// 328.622 us; speedup vs baseline: 2.0359x; 1.1007x over previous
//
#include <hip/hip_runtime.h>

// GCNEncoder: two GCNConv(+relu) layers + global mean pool.
// N=50000 nodes, E=1.6M edges, 128 ch, 64 graphs.
// R3: CSR build via two-level LDS counting sort — zero global atomics.
// (R2 flat atomic cap: 1.6M memory-side RMWs = ~70us regardless of privatization.)

#define CH 128
#define BSH 7        // 128 nodes per bucket
#define NBLK 256     // level-1 edge-chunk blocks
#define MAXNB 512    // LDS histogram capacity (NB = ceil(N/128) = 391)

static __device__ __forceinline__ unsigned short f2bf(float f) {
    unsigned u = __float_as_uint(f);
    unsigned r = (u + 0x7FFF + ((u >> 16) & 1)) >> 16;  // RNE
    return (unsigned short)r;
}

// ---- level-1 count: per-(bucket, chunk-block) histogram, LDS atomics only
__global__ __launch_bounds__(256) void k_sort1a(const int* __restrict__ col,
                                                int* __restrict__ H, int E, int NB, int chunk) {
    __shared__ int hist[MAXNB];
    int t = threadIdx.x, blk = blockIdx.x;
    for (int i = t; i < NB; i += 256) hist[i] = 0;
    __syncthreads();
    int s = blk * chunk, e1 = min(s + chunk, E);
    for (int e = s + t; e < e1; e += 256) atomicAdd(&hist[col[e] >> BSH], 1);
    __syncthreads();
    for (int i = t; i < NB; i += 256) H[(size_t)i * NBLK + blk] = hist[i];
}

// ---- 3-phase exclusive scan, in place over data[0..n) ----
__global__ __launch_bounds__(1024) void k_scan1(int* __restrict__ data,
                                                int* __restrict__ bsum, int n) {
    __shared__ int sd[1024];
    int t = threadIdx.x;
    int i = blockIdx.x * 1024 + t;
    int v = (i < n) ? data[i] : 0;
    sd[t] = v;
    __syncthreads();
    for (int off = 1; off < 1024; off <<= 1) {
        int u = (t >= off) ? sd[t - off] : 0;
        __syncthreads();
        sd[t] += u;
        __syncthreads();
    }
    if (i < n) data[i] = sd[t] - v;
    if (t == 1023) bsum[blockIdx.x] = sd[1023];
}

__global__ __launch_bounds__(64) void k_scan2(int* bsum, int nb, int* total) {
    int t = threadIdx.x;
    if (nb <= 64) {
        int v = (t < nb) ? bsum[t] : 0;
        int orig = v;
        for (int off = 1; off < 64; off <<= 1) {
            int u = __shfl_up(v, off);
            if (t >= off) v += u;
        }
        if (t < nb) bsum[t] = v - orig;
        if (t == nb - 1) *total = v;
    } else if (t == 0) {
        int run = 0;
        for (int i = 0; i < nb; ++i) { int c = bsum[i]; bsum[i] = run; run += c; }
        *total = run;
    }
}

__global__ void k_scan3(int* data, const int* __restrict__ bsum, int n) {
    int i = blockIdx.x * 256 + threadIdx.x;
    if (i < n) data[i] += bsum[i >> 10];
}

// ---- level-1 scatter into bucket order via LDS cursors (disjoint regions)
__global__ __launch_bounds__(256) void k_sort1b(const int* __restrict__ row,
                                                const int* __restrict__ col,
                                                const float* __restrict__ ew,
                                                const int* __restrict__ Hs,
                                                int* __restrict__ cbuf,
                                                int2* __restrict__ pairs2,
                                                int E, int NB, int chunk) {
    __shared__ int cur[MAXNB];
    int t = threadIdx.x, blk = blockIdx.x;
    for (int i = t; i < NB; i += 256) cur[i] = Hs[(size_t)i * NBLK + blk];
    __syncthreads();
    int s = blk * chunk, e1 = min(s + chunk, E);
    for (int e = s + t; e < e1; e += 256) {
        int c = col[e];
        int pos = atomicAdd(&cur[c >> BSH], 1);
        cbuf[pos] = c;
        pairs2[pos] = make_int2(row[e], __float_as_int(ew[e]));
    }
}

// ---- level-2: per-bucket node sort + rowptr, LDS atomics only
__global__ __launch_bounds__(256) void k_sort2(const int* __restrict__ Hs,
                                               const int* __restrict__ cbuf,
                                               const int2* __restrict__ pairs2,
                                               int2* __restrict__ pairs,
                                               int* __restrict__ rowptr,
                                               int E, int N, int NB) {
    __shared__ int hist[128];
    __shared__ int pref[128];
    int b = blockIdx.x, t = threadIdx.x;
    int n0 = b << BSH;
    int s = Hs[(size_t)b * NBLK];
    int e1 = (b + 1 < NB) ? Hs[(size_t)(b + 1) * NBLK] : E;
    if (t < 128) hist[t] = 0;
    __syncthreads();
    for (int e = s + t; e < e1; e += 256) atomicAdd(&hist[cbuf[e] - n0], 1);
    __syncthreads();
    if (t < 128) pref[t] = hist[t];
    __syncthreads();
    for (int off = 1; off < 128; off <<= 1) {
        int v = 0;
        if (t < 128 && t >= off) v = pref[t - off];
        __syncthreads();
        if (t < 128) pref[t] += v;
        __syncthreads();
    }
    if (t < 128) {
        int excl = pref[t] - hist[t];
        int node = n0 + t;
        if (node < N) rowptr[node] = s + excl;
        hist[t] = s + excl;  // cursor
    }
    if (b == NB - 1 && t == 0) rowptr[N] = E;
    __syncthreads();
    for (int e = s + t; e < e1; e += 256) {
        int pos = atomicAdd(&hist[cbuf[e] - n0], 1);
        pairs[pos] = pairs2[e];
    }
}

// dis[n] = rsqrt(1 + sum of incoming edge weights)
__global__ __launch_bounds__(64) void k_deg(const int* __restrict__ rowptr,
                                            const int2* __restrict__ pairs,
                                            float* __restrict__ dis, int N) {
    int n = blockIdx.x;
    int lane = threadIdx.x;
    int e0 = rowptr[n], e1 = rowptr[n + 1];
    float s = 0.f;
    for (int e = e0 + lane; e < e1; e += 64) s += __int_as_float(pairs[e].y);
    for (int off = 32; off; off >>= 1) s += __shfl_xor(s, off);
    if (lane == 0) dis[n] = rsqrtf(1.0f + s);
}

// pairs[e].y: weight -> norm = dis[n] * w * dis[src]
__global__ __launch_bounds__(64) void k_norm(const int* __restrict__ rowptr,
                                             int2* __restrict__ pairs,
                                             const float* __restrict__ dis, int N) {
    int n = blockIdx.x;
    int lane = threadIdx.x;
    float dn = dis[n];
    int e0 = rowptr[n], e1 = rowptr[n + 1];
    for (int e = e0 + lane; e < e1; e += 64) {
        int2 p = pairs[e];
        float nn = dn * __int_as_float(p.y) * dis[p.x];
        pairs[e].y = __float_as_int(nn);
    }
}

// Y[N,128](bf16) = X[N,128](f32) @ W[128,128](f32). W + 32-row X tile in LDS.
__global__ __launch_bounds__(256) void k_gemm(const float* __restrict__ X,
                                              const float* __restrict__ W,
                                              unsigned short* __restrict__ Y, int N) {
    __shared__ float Ws[128][128];
    __shared__ float Xs[32][128];
    int tid = threadIdx.x;
    {
        const float4* Wv = (const float4*)W;
        float4* Sv = (float4*)&Ws[0][0];
#pragma unroll
        for (int i = 0; i < 16; ++i) Sv[tid + 256 * i] = Wv[tid + 256 * i];
    }
    int row0 = blockIdx.x * 32;
    {
        float4* Xsv = (float4*)&Xs[0][0];
        if (row0 + 32 <= N) {
            const float4* Xv = (const float4*)(X + (size_t)row0 * CH);
#pragma unroll
            for (int i = 0; i < 4; ++i) { int idx = tid + 256 * i; Xsv[idx] = Xv[idx]; }
        } else {
#pragma unroll
            for (int i = 0; i < 4; ++i) {
                int idx = tid + 256 * i;
                int r = idx >> 5;
                float4 v = make_float4(0.f, 0.f, 0.f, 0.f);
                if (row0 + r < N) v = ((const float4*)(X + (size_t)(row0 + r) * CH))[idx & 31];
                Xsv[idx] = v;
            }
        }
    }
    __syncthreads();
    int c4 = tid & 31;
    int rl = tid >> 5;
    float4 acc[4];
#pragma unroll
    for (int j = 0; j < 4; ++j) acc[j] = make_float4(0.f, 0.f, 0.f, 0.f);
    for (int k = 0; k < 128; k += 4) {
        float4 w0 = *(const float4*)&Ws[k + 0][c4 * 4];
        float4 w1 = *(const float4*)&Ws[k + 1][c4 * 4];
        float4 w2 = *(const float4*)&Ws[k + 2][c4 * 4];
        float4 w3 = *(const float4*)&Ws[k + 3][c4 * 4];
#pragma unroll
        for (int j = 0; j < 4; ++j) {
            float4 xv = *(const float4*)&Xs[rl + 8 * j][k];
            acc[j].x += xv.x * w0.x + xv.y * w1.x + xv.z * w2.x + xv.w * w3.x;
            acc[j].y += xv.x * w0.y + xv.y * w1.y + xv.z * w2.y + xv.w * w3.y;
            acc[j].z += xv.x * w0.z + xv.y * w1.z + xv.z * w2.z + xv.w * w3.z;
            acc[j].w += xv.x * w0.w + xv.y * w1.w + xv.z * w2.w + xv.w * w3.w;
        }
    }
#pragma unroll
    for (int j = 0; j < 4; ++j) {
        int r = row0 + rl + 8 * j;
        if (r < N) {
            ushort4 o;
            o.x = f2bf(acc[j].x); o.y = f2bf(acc[j].y);
            o.z = f2bf(acc[j].z); o.w = f2bf(acc[j].w);
            *(ushort4*)&Y[(size_t)r * CH + c4 * 4] = o;
        }
    }
}

// One wave per node: out[n] = relu( selfnorm*xw[n] + sum_e nrm_e*xw[src_e] + b ).
__global__ __launch_bounds__(64) void k_agg(const unsigned int* __restrict__ XW,
                                            const float* __restrict__ dis,
                                            const int* __restrict__ rowptr,
                                            const int2* __restrict__ pairs,
                                            const float* __restrict__ bias,
                                            float* __restrict__ OUT, int N) {
    int n = blockIdx.x;
    if (n >= N) return;
    int lane = threadIdx.x;
    float d = dis[n];
    float sn = d * d;
    unsigned a = XW[(size_t)n * 64 + lane];
    float ax = __uint_as_float(a << 16) * sn;
    float ay = __uint_as_float(a & 0xFFFF0000u) * sn;
    int e0 = rowptr[n], e1 = rowptr[n + 1];
    int e = e0;
    for (; e + 4 <= e1; e += 4) {
        int2 p0 = pairs[e], p1 = pairs[e + 1], p2 = pairs[e + 2], p3 = pairs[e + 3];
        unsigned v0 = XW[(size_t)p0.x * 64 + lane];
        unsigned v1 = XW[(size_t)p1.x * 64 + lane];
        unsigned v2 = XW[(size_t)p2.x * 64 + lane];
        unsigned v3 = XW[(size_t)p3.x * 64 + lane];
        float n0 = __int_as_float(p0.y), n1 = __int_as_float(p1.y);
        float n2 = __int_as_float(p2.y), n3 = __int_as_float(p3.y);
        ax += n0 * __uint_as_float(v0 << 16) + n1 * __uint_as_float(v1 << 16)
            + n2 * __uint_as_float(v2 << 16) + n3 * __uint_as_float(v3 << 16);
        ay += n0 * __uint_as_float(v0 & 0xFFFF0000u) + n1 * __uint_as_float(v1 & 0xFFFF0000u)
            + n2 * __uint_as_float(v2 & 0xFFFF0000u) + n3 * __uint_as_float(v3 & 0xFFFF0000u);
    }
    for (; e < e1; ++e) {
        int2 p = pairs[e];
        unsigned v = XW[(size_t)p.x * 64 + lane];
        float nn = __int_as_float(p.y);
        ax += nn * __uint_as_float(v << 16);
        ay += nn * __uint_as_float(v & 0xFFFF0000u);
    }
    float2 b = ((const float2*)bias)[lane];
    ax = fmaxf(ax + b.x, 0.f);
    ay = fmaxf(ay + b.y, 0.f);
    ((float2*)OUT)[(size_t)n * 64 + lane] = make_float2(ax, ay);
}

__device__ __forceinline__ int lowerb(const int* a, int n, int v) {
    int lo = 0, hi = n;
    while (lo < hi) {
        int m = (lo + hi) >> 1;
        if (a[m] < v) lo = m + 1; else hi = m;
    }
    return lo;
}

__global__ __launch_bounds__(128) void k_pool(const float* __restrict__ H,
                                              const int* __restrict__ batch,
                                              float* __restrict__ P, int N) {
    __shared__ int ss[2];
    int g = blockIdx.x;
    if (threadIdx.x == 0) {
        ss[0] = lowerb(batch, N, g);
        ss[1] = lowerb(batch, N, g + 1);
    }
    __syncthreads();
    int s = ss[0], e = ss[1];
    int ch = threadIdx.x;
    float a0 = 0.f, a1 = 0.f, a2 = 0.f, a3 = 0.f;
    int n = s;
    for (; n + 4 <= e; n += 4) {
        a0 += H[(size_t)(n + 0) * CH + ch];
        a1 += H[(size_t)(n + 1) * CH + ch];
        a2 += H[(size_t)(n + 2) * CH + ch];
        a3 += H[(size_t)(n + 3) * CH + ch];
    }
    for (; n < e; ++n) a0 += H[(size_t)n * CH + ch];
    float sum = (a0 + a1) + (a2 + a3);
    float c = (float)(e - s);
    P[(size_t)g * CH + ch] = sum / fmaxf(c, 1.f);
}

extern "C" void kernel_launch(void* const* d_in, const int* in_sizes, int n_in,
                              void* d_out, int out_size, void* d_ws, size_t ws_size,
                              hipStream_t stream) {
    const float* x     = (const float*)d_in[0];
    const int*   ei    = (const int*)d_in[1];
    const float* ew    = (const float*)d_in[2];
    const int*   batch = (const int*)d_in[3];
    const float* W1    = (const float*)d_in[4];
    const float* b1    = (const float*)d_in[5];
    const float* W2    = (const float*)d_in[6];
    const float* b2    = (const float*)d_in[7];

    int N = in_sizes[0] / CH;   // 50000
    int E = in_sizes[1] / 2;    // 1600000
    const int* row = ei;
    const int* col = ei + E;

    float* out    = (float*)d_out;
    float* h      = out;
    float* pooled = out + (size_t)N * CH;

    int NB    = (N + 127) >> BSH;          // 391
    int chunk = (E + NBLK - 1) / NBLK;     // 6250
    int n2    = NB * NBLK;                 // 100096

    // ws: dis | rowptr | H(n2+1) | bsum | pairs | cbuf | xw(bf16; pairs2 aliases)
    char* wsb = (char*)d_ws;
    size_t oN  = ((size_t)N * 4 + 255) & ~(size_t)255;
    size_t oN1 = ((size_t)(N + 1) * 4 + 255) & ~(size_t)255;
    size_t oH  = ((size_t)(n2 + 1) * 4 + 255) & ~(size_t)255;
    size_t oB  = 512;
    size_t oE2 = ((size_t)E * 8 + 255) & ~(size_t)255;
    size_t oE1 = ((size_t)E * 4 + 255) & ~(size_t)255;
    float* dis    = (float*)wsb;
    int*   rowptr = (int*)(wsb + oN);
    int*   H      = (int*)(wsb + oN + oN1);
    int*   bsum   = (int*)(wsb + oN + oN1 + oH);
    int2*  pairs  = (int2*)(wsb + oN + oN1 + oH + oB);
    int*   cbuf   = (int*)(wsb + oN + oN1 + oH + oB + oE2);
    unsigned short* xw = (unsigned short*)(wsb + oN + oN1 + oH + oB + oE2 + oE1);
    int2*  pairs2 = (int2*)xw;  // E*8 = 12.8MB == N*CH*2; dead before k_gemm writes xw

    int sb2 = (n2 + 1023) / 1024;  // 98

    // ---- CSR build: two-level LDS counting sort (no global atomics) ----
    k_sort1a<<<NBLK, 256, 0, stream>>>(col, H, E, NB, chunk);
    k_scan1<<<sb2, 1024, 0, stream>>>(H, bsum, n2);
    k_scan2<<<1, 64, 0, stream>>>(bsum, sb2, H + n2);
    k_scan3<<<(n2 + 255) / 256, 256, 0, stream>>>(H, bsum, n2);
    k_sort1b<<<NBLK, 256, 0, stream>>>(row, col, ew, H, cbuf, pairs2, E, NB, chunk);
    k_sort2<<<NB, 256, 0, stream>>>(H, cbuf, pairs2, pairs, rowptr, E, N, NB);
    k_deg<<<N, 64, 0, stream>>>(rowptr, pairs, dis, N);
    k_norm<<<N, 64, 0, stream>>>(rowptr, pairs, dis, N);

    int gb = (N + 31) / 32;
    // ---- layer 1 ----
    k_gemm<<<gb, 256, 0, stream>>>(x, W1, xw, N);
    k_agg<<<N, 64, 0, stream>>>((const unsigned int*)xw, dis, rowptr, pairs, b1, h, N);
    // ---- layer 2 ----
    k_gemm<<<gb, 256, 0, stream>>>(h, W2, xw, N);
    k_agg<<<N, 64, 0, stream>>>((const unsigned int*)xw, dis, rowptr, pairs, b2, h, N);
    // ---- mean pool ----
    k_pool<<<64, 128, 0, stream>>>(h, batch, pooled, N);
}

// Round 5
// 274.669 us; speedup vs baseline: 2.4359x; 1.1964x over previous
//
#include <hip/hip_runtime.h>

// GCNEncoder: two GCNConv(+relu) layers + global mean pool.
// N=50000 nodes, E=1.6M edges, 128 ch, 64 graphs.
// R4: two-stage mean-pool (fix 1.2% occupancy), degree fused into sort2.

#define CH 128
#define BSH 7        // 128 nodes per bucket
#define NBLK 256     // level-1 edge-chunk blocks
#define MAXNB 512    // LDS histogram capacity (NB = ceil(N/128) = 391)
#define PCH 32       // pool chunks per graph

static __device__ __forceinline__ unsigned short f2bf(float f) {
    unsigned u = __float_as_uint(f);
    unsigned r = (u + 0x7FFF + ((u >> 16) & 1)) >> 16;  // RNE
    return (unsigned short)r;
}

// ---- level-1 count: per-(bucket, chunk-block) histogram, LDS atomics only
__global__ __launch_bounds__(256) void k_sort1a(const int* __restrict__ col,
                                                int* __restrict__ H, int E, int NB, int chunk) {
    __shared__ int hist[MAXNB];
    int t = threadIdx.x, blk = blockIdx.x;
    for (int i = t; i < NB; i += 256) hist[i] = 0;
    __syncthreads();
    int s = blk * chunk, e1 = min(s + chunk, E);
    for (int e = s + t; e < e1; e += 256) atomicAdd(&hist[col[e] >> BSH], 1);
    __syncthreads();
    for (int i = t; i < NB; i += 256) H[(size_t)i * NBLK + blk] = hist[i];
}

// ---- 3-phase exclusive scan, in place over data[0..n) ----
__global__ __launch_bounds__(1024) void k_scan1(int* __restrict__ data,
                                                int* __restrict__ bsum, int n) {
    __shared__ int sd[1024];
    int t = threadIdx.x;
    int i = blockIdx.x * 1024 + t;
    int v = (i < n) ? data[i] : 0;
    sd[t] = v;
    __syncthreads();
    for (int off = 1; off < 1024; off <<= 1) {
        int u = (t >= off) ? sd[t - off] : 0;
        __syncthreads();
        sd[t] += u;
        __syncthreads();
    }
    if (i < n) data[i] = sd[t] - v;
    if (t == 1023) bsum[blockIdx.x] = sd[1023];
}

__global__ __launch_bounds__(64) void k_scan2(int* bsum, int nb, int* total) {
    int t = threadIdx.x;
    if (nb <= 64) {
        int v = (t < nb) ? bsum[t] : 0;
        int orig = v;
        for (int off = 1; off < 64; off <<= 1) {
            int u = __shfl_up(v, off);
            if (t >= off) v += u;
        }
        if (t < nb) bsum[t] = v - orig;
        if (t == nb - 1) *total = v;
    } else if (t == 0) {
        int run = 0;
        for (int i = 0; i < nb; ++i) { int c = bsum[i]; bsum[i] = run; run += c; }
        *total = run;
    }
}

__global__ void k_scan3(int* data, const int* __restrict__ bsum, int n) {
    int i = blockIdx.x * 256 + threadIdx.x;
    if (i < n) data[i] += bsum[i >> 10];
}

// ---- level-1 scatter into bucket order via LDS cursors (disjoint regions)
__global__ __launch_bounds__(256) void k_sort1b(const int* __restrict__ row,
                                                const int* __restrict__ col,
                                                const float* __restrict__ ew,
                                                const int* __restrict__ Hs,
                                                int* __restrict__ cbuf,
                                                int2* __restrict__ pairs2,
                                                int E, int NB, int chunk) {
    __shared__ int cur[MAXNB];
    int t = threadIdx.x, blk = blockIdx.x;
    for (int i = t; i < NB; i += 256) cur[i] = Hs[(size_t)i * NBLK + blk];
    __syncthreads();
    int s = blk * chunk, e1 = min(s + chunk, E);
    for (int e = s + t; e < e1; e += 256) {
        int c = col[e];
        int pos = atomicAdd(&cur[c >> BSH], 1);
        cbuf[pos] = c;
        pairs2[pos] = make_int2(row[e], __float_as_int(ew[e]));
    }
}

// ---- level-2: per-bucket node sort + rowptr + degree (dis), LDS only
__global__ __launch_bounds__(256) void k_sort2(const int* __restrict__ Hs,
                                               const int* __restrict__ cbuf,
                                               const int2* __restrict__ pairs2,
                                               int2* __restrict__ pairs,
                                               int* __restrict__ rowptr,
                                               float* __restrict__ dis,
                                               int E, int N, int NB) {
    __shared__ int hist[128];
    __shared__ int pref[128];
    __shared__ float wsum[128];
    int b = blockIdx.x, t = threadIdx.x;
    int n0 = b << BSH;
    int s = Hs[(size_t)b * NBLK];
    int e1 = (b + 1 < NB) ? Hs[(size_t)(b + 1) * NBLK] : E;
    if (t < 128) { hist[t] = 0; wsum[t] = 0.f; }
    __syncthreads();
    for (int e = s + t; e < e1; e += 256) atomicAdd(&hist[cbuf[e] - n0], 1);
    __syncthreads();
    if (t < 128) pref[t] = hist[t];
    __syncthreads();
    for (int off = 1; off < 128; off <<= 1) {
        int v = 0;
        if (t < 128 && t >= off) v = pref[t - off];
        __syncthreads();
        if (t < 128) pref[t] += v;
        __syncthreads();
    }
    if (t < 128) {
        int excl = pref[t] - hist[t];
        int node = n0 + t;
        if (node < N) rowptr[node] = s + excl;
        hist[t] = s + excl;  // cursor
    }
    if (b == NB - 1 && t == 0) rowptr[N] = E;
    __syncthreads();
    for (int e = s + t; e < e1; e += 256) {
        int li = cbuf[e] - n0;
        int2 pr = pairs2[e];
        int pos = atomicAdd(&hist[li], 1);
        pairs[pos] = pr;
        atomicAdd(&wsum[li], __int_as_float(pr.y));
    }
    __syncthreads();
    if (t < 128 && n0 + t < N) dis[n0 + t] = rsqrtf(1.0f + wsum[t]);
}

// pairs[e].y: weight -> norm = dis[n] * w * dis[src]
__global__ __launch_bounds__(64) void k_norm(const int* __restrict__ rowptr,
                                             int2* __restrict__ pairs,
                                             const float* __restrict__ dis, int N) {
    int n = blockIdx.x;
    int lane = threadIdx.x;
    float dn = dis[n];
    int e0 = rowptr[n], e1 = rowptr[n + 1];
    for (int e = e0 + lane; e < e1; e += 64) {
        int2 p = pairs[e];
        float nn = dn * __int_as_float(p.y) * dis[p.x];
        pairs[e].y = __float_as_int(nn);
    }
}

// Y[N,128](bf16) = X[N,128](f32) @ W[128,128](f32). W + 32-row X tile in LDS.
__global__ __launch_bounds__(256) void k_gemm(const float* __restrict__ X,
                                              const float* __restrict__ W,
                                              unsigned short* __restrict__ Y, int N) {
    __shared__ float Ws[128][128];
    __shared__ float Xs[32][128];
    int tid = threadIdx.x;
    {
        const float4* Wv = (const float4*)W;
        float4* Sv = (float4*)&Ws[0][0];
#pragma unroll
        for (int i = 0; i < 16; ++i) Sv[tid + 256 * i] = Wv[tid + 256 * i];
    }
    int row0 = blockIdx.x * 32;
    {
        float4* Xsv = (float4*)&Xs[0][0];
        if (row0 + 32 <= N) {
            const float4* Xv = (const float4*)(X + (size_t)row0 * CH);
#pragma unroll
            for (int i = 0; i < 4; ++i) { int idx = tid + 256 * i; Xsv[idx] = Xv[idx]; }
        } else {
#pragma unroll
            for (int i = 0; i < 4; ++i) {
                int idx = tid + 256 * i;
                int r = idx >> 5;
                float4 v = make_float4(0.f, 0.f, 0.f, 0.f);
                if (row0 + r < N) v = ((const float4*)(X + (size_t)(row0 + r) * CH))[idx & 31];
                Xsv[idx] = v;
            }
        }
    }
    __syncthreads();
    int c4 = tid & 31;
    int rl = tid >> 5;
    float4 acc[4];
#pragma unroll
    for (int j = 0; j < 4; ++j) acc[j] = make_float4(0.f, 0.f, 0.f, 0.f);
    for (int k = 0; k < 128; k += 4) {
        float4 w0 = *(const float4*)&Ws[k + 0][c4 * 4];
        float4 w1 = *(const float4*)&Ws[k + 1][c4 * 4];
        float4 w2 = *(const float4*)&Ws[k + 2][c4 * 4];
        float4 w3 = *(const float4*)&Ws[k + 3][c4 * 4];
#pragma unroll
        for (int j = 0; j < 4; ++j) {
            float4 xv = *(const float4*)&Xs[rl + 8 * j][k];
            acc[j].x += xv.x * w0.x + xv.y * w1.x + xv.z * w2.x + xv.w * w3.x;
            acc[j].y += xv.x * w0.y + xv.y * w1.y + xv.z * w2.y + xv.w * w3.y;
            acc[j].z += xv.x * w0.z + xv.y * w1.z + xv.z * w2.z + xv.w * w3.z;
            acc[j].w += xv.x * w0.w + xv.y * w1.w + xv.z * w2.w + xv.w * w3.w;
        }
    }
#pragma unroll
    for (int j = 0; j < 4; ++j) {
        int r = row0 + rl + 8 * j;
        if (r < N) {
            ushort4 o;
            o.x = f2bf(acc[j].x); o.y = f2bf(acc[j].y);
            o.z = f2bf(acc[j].z); o.w = f2bf(acc[j].w);
            *(ushort4*)&Y[(size_t)r * CH + c4 * 4] = o;
        }
    }
}

// One wave per node: out[n] = relu( selfnorm*xw[n] + sum_e nrm_e*xw[src_e] + b ).
__global__ __launch_bounds__(64) void k_agg(const unsigned int* __restrict__ XW,
                                            const float* __restrict__ dis,
                                            const int* __restrict__ rowptr,
                                            const int2* __restrict__ pairs,
                                            const float* __restrict__ bias,
                                            float* __restrict__ OUT, int N) {
    int n = blockIdx.x;
    if (n >= N) return;
    int lane = threadIdx.x;
    float d = dis[n];
    float sn = d * d;
    unsigned a = XW[(size_t)n * 64 + lane];
    float ax = __uint_as_float(a << 16) * sn;
    float ay = __uint_as_float(a & 0xFFFF0000u) * sn;
    int e0 = rowptr[n], e1 = rowptr[n + 1];
    int e = e0;
    for (; e + 4 <= e1; e += 4) {
        int2 p0 = pairs[e], p1 = pairs[e + 1], p2 = pairs[e + 2], p3 = pairs[e + 3];
        unsigned v0 = XW[(size_t)p0.x * 64 + lane];
        unsigned v1 = XW[(size_t)p1.x * 64 + lane];
        unsigned v2 = XW[(size_t)p2.x * 64 + lane];
        unsigned v3 = XW[(size_t)p3.x * 64 + lane];
        float n0 = __int_as_float(p0.y), n1 = __int_as_float(p1.y);
        float n2 = __int_as_float(p2.y), n3 = __int_as_float(p3.y);
        ax += n0 * __uint_as_float(v0 << 16) + n1 * __uint_as_float(v1 << 16)
            + n2 * __uint_as_float(v2 << 16) + n3 * __uint_as_float(v3 << 16);
        ay += n0 * __uint_as_float(v0 & 0xFFFF0000u) + n1 * __uint_as_float(v1 & 0xFFFF0000u)
            + n2 * __uint_as_float(v2 & 0xFFFF0000u) + n3 * __uint_as_float(v3 & 0xFFFF0000u);
    }
    for (; e < e1; ++e) {
        int2 p = pairs[e];
        unsigned v = XW[(size_t)p.x * 64 + lane];
        float nn = __int_as_float(p.y);
        ax += nn * __uint_as_float(v << 16);
        ay += nn * __uint_as_float(v & 0xFFFF0000u);
    }
    float2 b = ((const float2*)bias)[lane];
    ax = fmaxf(ax + b.x, 0.f);
    ay = fmaxf(ay + b.y, 0.f);
    ((float2*)OUT)[(size_t)n * 64 + lane] = make_float2(ax, ay);
}

__device__ __forceinline__ int lowerb(const int* a, int n, int v) {
    int lo = 0, hi = n;
    while (lo < hi) {
        int m = (lo + hi) >> 1;
        if (a[m] < v) lo = m + 1; else hi = m;
    }
    return lo;
}

// Stage 1: 64 graphs x PCH chunks, partial channel sums.
__global__ __launch_bounds__(128) void k_pool1(const float* __restrict__ H,
                                               const int* __restrict__ batch,
                                               float* __restrict__ partial, int N) {
    __shared__ int ss[2];
    int g = blockIdx.x / PCH;
    int k = blockIdx.x % PCH;
    if (threadIdx.x == 0) {
        ss[0] = lowerb(batch, N, g);
        ss[1] = lowerb(batch, N, g + 1);
    }
    __syncthreads();
    int s = ss[0], len = ss[1] - ss[0];
    int cs = s + (int)(((long long)len * k) / PCH);
    int ce = s + (int)(((long long)len * (k + 1)) / PCH);
    int ch = threadIdx.x;
    float a0 = 0.f, a1 = 0.f;
    int n = cs;
    for (; n + 2 <= ce; n += 2) {
        a0 += H[(size_t)(n + 0) * CH + ch];
        a1 += H[(size_t)(n + 1) * CH + ch];
    }
    for (; n < ce; ++n) a0 += H[(size_t)n * CH + ch];
    partial[(size_t)blockIdx.x * CH + ch] = a0 + a1;
}

// Stage 2: reduce PCH partials per graph, divide by count.
__global__ __launch_bounds__(128) void k_pool2(const float* __restrict__ partial,
                                               const int* __restrict__ batch,
                                               float* __restrict__ P, int N) {
    __shared__ int ss[2];
    int g = blockIdx.x;
    if (threadIdx.x == 0) {
        ss[0] = lowerb(batch, N, g);
        ss[1] = lowerb(batch, N, g + 1);
    }
    __syncthreads();
    int ch = threadIdx.x;
    float a = 0.f;
#pragma unroll
    for (int k = 0; k < PCH; ++k) a += partial[(size_t)(g * PCH + k) * CH + ch];
    float c = (float)(ss[1] - ss[0]);
    P[(size_t)g * CH + ch] = a / fmaxf(c, 1.f);
}

extern "C" void kernel_launch(void* const* d_in, const int* in_sizes, int n_in,
                              void* d_out, int out_size, void* d_ws, size_t ws_size,
                              hipStream_t stream) {
    const float* x     = (const float*)d_in[0];
    const int*   ei    = (const int*)d_in[1];
    const float* ew    = (const float*)d_in[2];
    const int*   batch = (const int*)d_in[3];
    const float* W1    = (const float*)d_in[4];
    const float* b1    = (const float*)d_in[5];
    const float* W2    = (const float*)d_in[6];
    const float* b2    = (const float*)d_in[7];

    int N = in_sizes[0] / CH;   // 50000
    int E = in_sizes[1] / 2;    // 1600000
    const int* row = ei;
    const int* col = ei + E;

    float* out    = (float*)d_out;
    float* h      = out;
    float* pooled = out + (size_t)N * CH;

    int NB    = (N + 127) >> BSH;          // 391
    int chunk = (E + NBLK - 1) / NBLK;     // 6250
    int n2    = NB * NBLK;                 // 100096

    // ws: dis | rowptr | H(n2+1) | bsum | pairs | cbuf | xw(bf16; pairs2 aliases)
    char* wsb = (char*)d_ws;
    size_t oN  = ((size_t)N * 4 + 255) & ~(size_t)255;
    size_t oN1 = ((size_t)(N + 1) * 4 + 255) & ~(size_t)255;
    size_t oH  = ((size_t)(n2 + 1) * 4 + 255) & ~(size_t)255;
    size_t oB  = 512;
    size_t oE2 = ((size_t)E * 8 + 255) & ~(size_t)255;
    size_t oE1 = ((size_t)E * 4 + 255) & ~(size_t)255;
    float* dis    = (float*)wsb;
    int*   rowptr = (int*)(wsb + oN);
    int*   H      = (int*)(wsb + oN + oN1);
    int*   bsum   = (int*)(wsb + oN + oN1 + oH);
    int2*  pairs  = (int2*)(wsb + oN + oN1 + oH + oB);
    int*   cbuf   = (int*)(wsb + oN + oN1 + oH + oB + oE2);
    unsigned short* xw = (unsigned short*)(wsb + oN + oN1 + oH + oB + oE2 + oE1);
    int2*  pairs2 = (int2*)xw;      // dead before k_gemm writes xw
    float* partial = (float*)cbuf;  // dead after k_sort2; 64*PCH*128*4B = 1MB < 6.4MB

    int sb2 = (n2 + 1023) / 1024;

    // ---- CSR build: two-level LDS counting sort (no global atomics) ----
    k_sort1a<<<NBLK, 256, 0, stream>>>(col, H, E, NB, chunk);
    k_scan1<<<sb2, 1024, 0, stream>>>(H, bsum, n2);
    k_scan2<<<1, 64, 0, stream>>>(bsum, sb2, H + n2);
    k_scan3<<<(n2 + 255) / 256, 256, 0, stream>>>(H, bsum, n2);
    k_sort1b<<<NBLK, 256, 0, stream>>>(row, col, ew, H, cbuf, pairs2, E, NB, chunk);
    k_sort2<<<NB, 256, 0, stream>>>(H, cbuf, pairs2, pairs, rowptr, dis, E, N, NB);
    k_norm<<<N, 64, 0, stream>>>(rowptr, pairs, dis, N);

    int gb = (N + 31) / 32;
    // ---- layer 1 ----
    k_gemm<<<gb, 256, 0, stream>>>(x, W1, xw, N);
    k_agg<<<N, 64, 0, stream>>>((const unsigned int*)xw, dis, rowptr, pairs, b1, h, N);
    // ---- layer 2 ----
    k_gemm<<<gb, 256, 0, stream>>>(h, W2, xw, N);
    k_agg<<<N, 64, 0, stream>>>((const unsigned int*)xw, dis, rowptr, pairs, b2, h, N);
    // ---- mean pool (two-stage) ----
    k_pool1<<<64 * PCH, 128, 0, stream>>>(h, batch, partial, N);
    k_pool2<<<64, 128, 0, stream>>>(partial, batch, pooled, N);
}